// Round 1
// baseline (555.523 us; speedup 1.0000x reference)
//
#include <hip/hip_runtime.h>

#define D 128            // feature dim
#define K2 256           // concat dim

// ---------------- CSR build ----------------

__global__ void hist_kernel(const int* __restrict__ idx, int* __restrict__ cnt, int n) {
    int e = blockIdx.x * 256 + threadIdx.x;
    if (e < n) atomicAdd(&cnt[idx[e]], 1);
}

__global__ void reduce_kernel(const int* __restrict__ cnt, int* __restrict__ bsum, int n) {
    __shared__ int s[256];
    int i = blockIdx.x * 256 + threadIdx.x;
    s[threadIdx.x] = (i < n) ? cnt[i] : 0;
    __syncthreads();
    for (int d = 128; d > 0; d >>= 1) {
        if (threadIdx.x < d) s[threadIdx.x] += s[threadIdx.x + d];
        __syncthreads();
    }
    if (threadIdx.x == 0) bsum[blockIdx.x] = s[0];
}

// single block; nb <= 256. Turns bsum into its exclusive scan, writes off[n]=total.
__global__ void scan_bsum_kernel(int* __restrict__ bsum, int* __restrict__ off, int nb, int n) {
    __shared__ int s[256];
    int v = (threadIdx.x < nb) ? bsum[threadIdx.x] : 0;
    s[threadIdx.x] = v;
    __syncthreads();
    for (int d = 1; d < 256; d <<= 1) {
        int t = (threadIdx.x >= d) ? s[threadIdx.x - d] : 0;
        __syncthreads();
        s[threadIdx.x] += t;
        __syncthreads();
    }
    if (threadIdx.x < nb) bsum[threadIdx.x] = s[threadIdx.x] - v;  // exclusive
    if (threadIdx.x == 255) off[n] = s[255];                        // grand total
}

__global__ void scan_kernel(const int* __restrict__ cnt, const int* __restrict__ bsum,
                            int* __restrict__ off, int* __restrict__ cur, int n) {
    __shared__ int s[256];
    int i = blockIdx.x * 256 + threadIdx.x;
    int v = (i < n) ? cnt[i] : 0;
    s[threadIdx.x] = v;
    __syncthreads();
    for (int d = 1; d < 256; d <<= 1) {
        int t = (threadIdx.x >= d) ? s[threadIdx.x - d] : 0;
        __syncthreads();
        s[threadIdx.x] += t;
        __syncthreads();
    }
    if (i < n) {
        int e = bsum[blockIdx.x] + s[threadIdx.x] - v;
        off[i] = e;
        cur[i] = e;
    }
}

__global__ void scatter_kernel(const int* __restrict__ idx, int* __restrict__ cur,
                               int* __restrict__ eid, int n) {
    int e = blockIdx.x * 256 + threadIdx.x;
    if (e < n) {
        int p = atomicAdd(&cur[idx[e]], 1);
        eid[p] = e;
    }
}

// ---------------- aggregate: one wave per node, gather + mean ----------------

__global__ __launch_bounds__(64) void aggregate_kernel(const float* __restrict__ nbr,
                                                       const int* __restrict__ eid,
                                                       const int* __restrict__ off,
                                                       float* __restrict__ agg) {
    const int node = blockIdx.x;
    const int beg = off[node], end = off[node + 1];
    const int t = threadIdx.x;
    const float2* rows = (const float2*)nbr;
    float2 acc = make_float2(0.f, 0.f);
    int j = beg;
    for (; j + 4 <= end; j += 4) {
        int e0 = eid[j], e1 = eid[j + 1], e2 = eid[j + 2], e3 = eid[j + 3];
        float2 v0 = rows[(size_t)e0 * 64 + t];
        float2 v1 = rows[(size_t)e1 * 64 + t];
        float2 v2 = rows[(size_t)e2 * 64 + t];
        float2 v3 = rows[(size_t)e3 * 64 + t];
        acc.x += (v0.x + v1.x) + (v2.x + v3.x);
        acc.y += (v0.y + v1.y) + (v2.y + v3.y);
    }
    for (; j < end; ++j) {
        int e = eid[j];
        float2 v = rows[(size_t)e * 64 + t];
        acc.x += v.x;
        acc.y += v.y;
    }
    int c = end - beg;
    float inv = (c > 0) ? 1.0f / (float)c : 0.0f;
    ((float2*)agg)[(size_t)node * 64 + t] = make_float2(acc.x * inv, acc.y * inv);
}

// ---------------- fused concat-matmul: out = [self | agg] @ W ----------------
// 64 rows x 128 cols per block, 128 threads, 8x8 f32 accumulators per thread.

#define MT 64
#define KB 32

__global__ __launch_bounds__(128) void matmul_kernel(const float* __restrict__ self,
                                                     const float* __restrict__ agg,
                                                     const float* __restrict__ W,
                                                     float* __restrict__ out, int nNodes) {
    __shared__ float Xs[KB][MT];    // transposed: Xs[k][m]
    __shared__ float Ws[KB][D];     // Ws[k][n]
    const int t = threadIdx.x;
    const int m_base = blockIdx.x * MT;
    const int n0 = (t & 15) * 8;    // 16 col groups
    const int m0 = (t >> 4) * 8;    // 8 row groups

    float acc[8][8];
#pragma unroll
    for (int i = 0; i < 8; ++i)
#pragma unroll
        for (int j = 0; j < 8; ++j) acc[i][j] = 0.f;

    for (int k0 = 0; k0 < K2; k0 += KB) {
        const float* src = (k0 < D) ? self : agg;
        const int koff = k0 & (D - 1);
        // stage X tile: 64 rows x 32 k = 512 float4, 4 per thread; transpose into Xs[k][m]
#pragma unroll
        for (int it = 0; it < 4; ++it) {
            int lin = t + it * 128;          // float4 index; 8 float4 per row
            int row = lin >> 3;
            int k4 = lin & 7;
            int gr = m_base + row;
            if (gr >= nNodes) gr = nNodes - 1;
            float4 v = *(const float4*)(src + (size_t)gr * D + koff + k4 * 4);
            Xs[k4 * 4 + 0][row] = v.x;
            Xs[k4 * 4 + 1][row] = v.y;
            Xs[k4 * 4 + 2][row] = v.z;
            Xs[k4 * 4 + 3][row] = v.w;
        }
        // stage W tile: 32 k x 128 n = 1024 float4, 8 per thread
#pragma unroll
        for (int it = 0; it < 8; ++it) {
            int lin = t + it * 128;          // 32 float4 per k-row
            int kk = lin >> 5;
            int n4 = lin & 31;
            *(float4*)(&Ws[kk][n4 * 4]) = *(const float4*)(W + (size_t)(k0 + kk) * D + n4 * 4);
        }
        __syncthreads();

#pragma unroll
        for (int kk4 = 0; kk4 < KB / 4; ++kk4) {
            float4 xa[4], xb[4], wa[4], wb[4];
#pragma unroll
            for (int kq = 0; kq < 4; ++kq) {
                int k = kk4 * 4 + kq;
                xa[kq] = *(const float4*)(&Xs[k][m0]);
                xb[kq] = *(const float4*)(&Xs[k][m0 + 4]);
                wa[kq] = *(const float4*)(&Ws[k][n0]);
                wb[kq] = *(const float4*)(&Ws[k][n0 + 4]);
            }
#pragma unroll
            for (int kq = 0; kq < 4; ++kq) {
                const float xr[8] = {xa[kq].x, xa[kq].y, xa[kq].z, xa[kq].w,
                                     xb[kq].x, xb[kq].y, xb[kq].z, xb[kq].w};
                const float wr[8] = {wa[kq].x, wa[kq].y, wa[kq].z, wa[kq].w,
                                     wb[kq].x, wb[kq].y, wb[kq].z, wb[kq].w};
#pragma unroll
                for (int i = 0; i < 8; ++i)
#pragma unroll
                    for (int j = 0; j < 8; ++j) acc[i][j] += xr[i] * wr[j];
            }
        }
        __syncthreads();
    }

#pragma unroll
    for (int i = 0; i < 8; ++i) {
        int gr = m_base + m0 + i;
        if (gr < nNodes) {
            float4 o0 = make_float4(acc[i][0], acc[i][1], acc[i][2], acc[i][3]);
            float4 o1 = make_float4(acc[i][4], acc[i][5], acc[i][6], acc[i][7]);
            *(float4*)(out + (size_t)gr * D + n0) = o0;
            *(float4*)(out + (size_t)gr * D + n0 + 4) = o1;
        }
    }
}

// ---------------- launch ----------------

extern "C" void kernel_launch(void* const* d_in, const int* in_sizes, int n_in,
                              void* d_out, int out_size, void* d_ws, size_t ws_size,
                              hipStream_t stream) {
    const float* self = (const float*)d_in[0];
    const float* nbr = (const float*)d_in[1];
    const int* idx = (const int*)d_in[2];
    const float* W = (const float*)d_in[3];
    float* out = (float*)d_out;

    const int nNodes = in_sizes[0] / D;   // 50000
    const int nEdges = in_sizes[2];       // 600000
    const int nb = (nNodes + 255) / 256;  // 196 scan blocks

    int* cnt = (int*)d_ws;                // nNodes
    int* off = cnt + nNodes;              // nNodes+1
    int* cur = off + (nNodes + 1);        // nNodes
    int* bsum = cur + nNodes;             // 256 (padded)
    int* eid = bsum + 256;                // nEdges

    hipMemsetAsync(cnt, 0, (size_t)nNodes * sizeof(int), stream);
    hist_kernel<<<(nEdges + 255) / 256, 256, 0, stream>>>(idx, cnt, nEdges);
    reduce_kernel<<<nb, 256, 0, stream>>>(cnt, bsum, nNodes);
    scan_bsum_kernel<<<1, 256, 0, stream>>>(bsum, off, nb, nNodes);
    scan_kernel<<<nb, 256, 0, stream>>>(cnt, bsum, off, cur, nNodes);
    scatter_kernel<<<(nEdges + 255) / 256, 256, 0, stream>>>(idx, cur, eid, nEdges);

    // agg is staged in d_out (exactly nNodes*D floats); matmul reads it per-tile
    // strictly before writing the same rows.
    aggregate_kernel<<<nNodes, 64, 0, stream>>>(nbr, eid, off, out);
    matmul_kernel<<<(nNodes + MT - 1) / MT, 128, 0, stream>>>(self, out, W, out, nNodes);
}

// Round 2
// 531.804 us; speedup vs baseline: 1.0446x; 1.0446x over previous
//
#include <hip/hip_runtime.h>

#define D 128            // feature dim
#define K2 256           // concat dim

typedef float vfloat4 __attribute__((ext_vector_type(4)));

// ---------------- CSR build ----------------

__global__ void hist_kernel(const int* __restrict__ idx, int* __restrict__ cnt, int n) {
    int e = blockIdx.x * 256 + threadIdx.x;
    if (e < n) atomicAdd(&cnt[idx[e]], 1);
}

__global__ void reduce_kernel(const int* __restrict__ cnt, int* __restrict__ bsum, int n) {
    __shared__ int s[256];
    int i = blockIdx.x * 256 + threadIdx.x;
    s[threadIdx.x] = (i < n) ? cnt[i] : 0;
    __syncthreads();
    for (int d = 128; d > 0; d >>= 1) {
        if (threadIdx.x < d) s[threadIdx.x] += s[threadIdx.x + d];
        __syncthreads();
    }
    if (threadIdx.x == 0) bsum[blockIdx.x] = s[0];
}

// single block; nb <= 256. Turns bsum into its exclusive scan, writes off[n]=total.
__global__ void scan_bsum_kernel(int* __restrict__ bsum, int* __restrict__ off, int nb, int n) {
    __shared__ int s[256];
    int v = (threadIdx.x < nb) ? bsum[threadIdx.x] : 0;
    s[threadIdx.x] = v;
    __syncthreads();
    for (int d = 1; d < 256; d <<= 1) {
        int t = (threadIdx.x >= d) ? s[threadIdx.x - d] : 0;
        __syncthreads();
        s[threadIdx.x] += t;
        __syncthreads();
    }
    if (threadIdx.x < nb) bsum[threadIdx.x] = s[threadIdx.x] - v;  // exclusive
    if (threadIdx.x == 255) off[n] = s[255];                        // grand total
}

__global__ void scan_kernel(const int* __restrict__ cnt, const int* __restrict__ bsum,
                            int* __restrict__ off, int* __restrict__ cur, int n) {
    __shared__ int s[256];
    int i = blockIdx.x * 256 + threadIdx.x;
    int v = (i < n) ? cnt[i] : 0;
    s[threadIdx.x] = v;
    __syncthreads();
    for (int d = 1; d < 256; d <<= 1) {
        int t = (threadIdx.x >= d) ? s[threadIdx.x - d] : 0;
        __syncthreads();
        s[threadIdx.x] += t;
        __syncthreads();
    }
    if (i < n) {
        int e = bsum[blockIdx.x] + s[threadIdx.x] - v;
        off[i] = e;
        cur[i] = e;
    }
}

__global__ void scatter_kernel(const int* __restrict__ idx, int* __restrict__ cur,
                               int* __restrict__ eid, int n) {
    int e = blockIdx.x * 256 + threadIdx.x;
    if (e < n) {
        int p = atomicAdd(&cur[idx[e]], 1);
        eid[p] = e;
    }
}

// ---------------- aggregate: one wave per node, 2 rows/iter-step, mean ----------------
// lanes 0-31 cover row j+h(=0), lanes 32-63 row j+h(=1); float4 per lane = 512 B/row.

__global__ __launch_bounds__(64) void aggregate_kernel(const float* __restrict__ nbr,
                                                       const int* __restrict__ eid,
                                                       const int* __restrict__ off,
                                                       float* __restrict__ agg) {
    const int node = blockIdx.x;
    const int beg = off[node], end = off[node + 1];
    const int t = threadIdx.x;
    const int h = t >> 5;       // which row of the pair
    const int l = t & 31;       // float4 index within the row (32 x 16B = 512B)
    const vfloat4* __restrict__ rows = (const vfloat4*)nbr;
    vfloat4 acc = {0.f, 0.f, 0.f, 0.f};
    int j = beg;
    // 8 rows per iteration: 4 x 512B gathers in flight per wave
    for (; j + 8 <= end; j += 8) {
        int e0 = eid[j + 0 + h];
        int e1 = eid[j + 2 + h];
        int e2 = eid[j + 4 + h];
        int e3 = eid[j + 6 + h];
        vfloat4 v0 = __builtin_nontemporal_load(rows + (size_t)e0 * 32 + l);
        vfloat4 v1 = __builtin_nontemporal_load(rows + (size_t)e1 * 32 + l);
        vfloat4 v2 = __builtin_nontemporal_load(rows + (size_t)e2 * 32 + l);
        vfloat4 v3 = __builtin_nontemporal_load(rows + (size_t)e3 * 32 + l);
        acc += (v0 + v1) + (v2 + v3);
    }
    if (j + 4 <= end) {  // 4-row step
        int e0 = eid[j + 0 + h];
        int e1 = eid[j + 2 + h];
        vfloat4 v0 = __builtin_nontemporal_load(rows + (size_t)e0 * 32 + l);
        vfloat4 v1 = __builtin_nontemporal_load(rows + (size_t)e1 * 32 + l);
        acc += v0 + v1;
        j += 4;
    }
    for (; j < end; j += 2) {  // 0..3 rows remain, 2 at a time
        int jj = j + h;
        if (jj < end) {
            int e = eid[jj];
            vfloat4 v = __builtin_nontemporal_load(rows + (size_t)e * 32 + l);
            acc += v;
        }
    }
    // combine the two half-wave partial sums
    acc.x += __shfl_xor(acc.x, 32);
    acc.y += __shfl_xor(acc.y, 32);
    acc.z += __shfl_xor(acc.z, 32);
    acc.w += __shfl_xor(acc.w, 32);
    int c = end - beg;
    float inv = (c > 0) ? 1.0f / (float)c : 0.0f;
    if (h == 0) {
        vfloat4 o = acc * inv;
        *((vfloat4*)agg + (size_t)node * 32 + l) = o;
    }
}

// ---------------- fused concat-matmul: out = [self | agg] @ W ----------------
// 64 rows x 128 cols per block, 128 threads, 8x8 f32 accumulators per thread.

#define MT 64
#define KB 32
#define XP (MT + 4)   // pad: write bank = (4*kk + row)%32 -> 4-way max; b128 reads stay 16B-aligned

__global__ __launch_bounds__(128) void matmul_kernel(const float* __restrict__ self,
                                                     const float* __restrict__ agg,
                                                     const float* __restrict__ W,
                                                     float* __restrict__ out, int nNodes) {
    __shared__ float Xs[KB][XP];    // transposed: Xs[k][m]
    __shared__ float Ws[KB][D];     // Ws[k][n]
    const int t = threadIdx.x;
    const int m_base = blockIdx.x * MT;
    const int n0 = (t & 15) * 8;    // 16 col groups
    const int m0 = (t >> 4) * 8;    // 8 row groups

    float acc[8][8];
#pragma unroll
    for (int i = 0; i < 8; ++i)
#pragma unroll
        for (int j = 0; j < 8; ++j) acc[i][j] = 0.f;

    for (int k0 = 0; k0 < K2; k0 += KB) {
        const float* src = (k0 < D) ? self : agg;
        const int koff = k0 & (D - 1);
        // stage X tile: 64 rows x 32 k = 512 float4, 4 per thread; transpose into Xs[k][m]
#pragma unroll
        for (int it = 0; it < 4; ++it) {
            int lin = t + it * 128;          // float4 index; 8 float4 per row
            int row = lin >> 3;
            int k4 = lin & 7;
            int gr = m_base + row;
            if (gr >= nNodes) gr = nNodes - 1;
            float4 v = *(const float4*)(src + (size_t)gr * D + koff + k4 * 4);
            Xs[k4 * 4 + 0][row] = v.x;
            Xs[k4 * 4 + 1][row] = v.y;
            Xs[k4 * 4 + 2][row] = v.z;
            Xs[k4 * 4 + 3][row] = v.w;
        }
        // stage W tile: 32 k x 128 n = 1024 float4, 8 per thread
#pragma unroll
        for (int it = 0; it < 8; ++it) {
            int lin = t + it * 128;          // 32 float4 per k-row
            int kk = lin >> 5;
            int n4 = lin & 31;
            *(float4*)(&Ws[kk][n4 * 4]) = *(const float4*)(W + (size_t)(k0 + kk) * D + n4 * 4);
        }
        __syncthreads();

#pragma unroll
        for (int kk4 = 0; kk4 < KB / 4; ++kk4) {
            float4 xa[4], xb[4], wa[4], wb[4];
#pragma unroll
            for (int kq = 0; kq < 4; ++kq) {
                int k = kk4 * 4 + kq;
                xa[kq] = *(const float4*)(&Xs[k][m0]);
                xb[kq] = *(const float4*)(&Xs[k][m0 + 4]);
                wa[kq] = *(const float4*)(&Ws[k][n0]);
                wb[kq] = *(const float4*)(&Ws[k][n0 + 4]);
            }
#pragma unroll
            for (int kq = 0; kq < 4; ++kq) {
                const float xr[8] = {xa[kq].x, xa[kq].y, xa[kq].z, xa[kq].w,
                                     xb[kq].x, xb[kq].y, xb[kq].z, xb[kq].w};
                const float wr[8] = {wa[kq].x, wa[kq].y, wa[kq].z, wa[kq].w,
                                     wb[kq].x, wb[kq].y, wb[kq].z, wb[kq].w};
#pragma unroll
                for (int i = 0; i < 8; ++i)
#pragma unroll
                    for (int j = 0; j < 8; ++j) acc[i][j] += xr[i] * wr[j];
            }
        }
        __syncthreads();
    }

#pragma unroll
    for (int i = 0; i < 8; ++i) {
        int gr = m_base + m0 + i;
        if (gr < nNodes) {
            float4 o0 = make_float4(acc[i][0], acc[i][1], acc[i][2], acc[i][3]);
            float4 o1 = make_float4(acc[i][4], acc[i][5], acc[i][6], acc[i][7]);
            *(float4*)(out + (size_t)gr * D + n0) = o0;
            *(float4*)(out + (size_t)gr * D + n0 + 4) = o1;
        }
    }
}

// ---------------- launch ----------------

extern "C" void kernel_launch(void* const* d_in, const int* in_sizes, int n_in,
                              void* d_out, int out_size, void* d_ws, size_t ws_size,
                              hipStream_t stream) {
    const float* self = (const float*)d_in[0];
    const float* nbr = (const float*)d_in[1];
    const int* idx = (const int*)d_in[2];
    const float* W = (const float*)d_in[3];
    float* out = (float*)d_out;

    const int nNodes = in_sizes[0] / D;   // 50000
    const int nEdges = in_sizes[2];       // 600000
    const int nb = (nNodes + 255) / 256;  // 196 scan blocks

    int* cnt = (int*)d_ws;                // nNodes
    int* off = cnt + nNodes;              // nNodes+1
    int* cur = off + (nNodes + 1);        // nNodes
    int* bsum = cur + nNodes;             // 256 (padded)
    int* eid = bsum + 256;                // nEdges

    hipMemsetAsync(cnt, 0, (size_t)nNodes * sizeof(int), stream);
    hist_kernel<<<(nEdges + 255) / 256, 256, 0, stream>>>(idx, cnt, nEdges);
    reduce_kernel<<<nb, 256, 0, stream>>>(cnt, bsum, nNodes);
    scan_bsum_kernel<<<1, 256, 0, stream>>>(bsum, off, nb, nNodes);
    scan_kernel<<<nb, 256, 0, stream>>>(cnt, bsum, off, cur, nNodes);
    scatter_kernel<<<(nEdges + 255) / 256, 256, 0, stream>>>(idx, cur, eid, nEdges);

    // agg is staged in d_out (exactly nNodes*D floats); matmul reads it per-tile
    // strictly before writing the same rows.
    aggregate_kernel<<<nNodes, 64, 0, stream>>>(nbr, eid, off, out);
    matmul_kernel<<<(nNodes + MT - 1) / MT, 128, 0, stream>>>(self, out, W, out, nNodes);
}